// Round 1
// 179.431 us; speedup vs baseline: 1.0626x; 1.0626x over previous
//
#include <hip/hip_runtime.h>
#include <math.h>

// BioREDirect, 2-kernel, bf16-everywhere edition.
// K1 (1024 thr, 192 blocks): attention-pool (unchanged verified gather/softmax
//     structure); now emits pooled as bf16 AND converts dW f32->bf16 using the
//     grid's idle capacity (12 rows per block => 768 rows per g). b==0 blocks
//     bias-init out[].
// K2 (512 thr, 36 blocks): single-stage MFMA. 96KB bf16 P-panel staged ONCE
//     into XOR-swizzled LDS (conflict-free b128 both sides); A-fragments
//     preloaded from global bf16 into regs; 8 waves = 2-way K-split x 4 m-tiles;
//     3 barriers total (was 24). LDS partial reduce + tanh + fused classifier.
// NOTE: ~150us of the timed iteration is harness restore/poison fills (fixed):
//     402 MB ws-poison fill ~60us + input restore ~60us + gaps.

#define Hdim 768
#define Kdim 64
#define Sdim 512
#define Bdim 64

typedef float f32x4 __attribute__((ext_vector_type(4)));
typedef short bf16x8 __attribute__((ext_vector_type(8)));

__device__ __forceinline__ unsigned short f2bf(float f) {
    union { float f; unsigned int u; } c; c.f = f;
    unsigned int u = c.u + 0x7FFFu + ((c.u >> 16) & 1u);  // RNE
    return (unsigned short)(u >> 16);
}

// ---------------- K1: attention pooling + operand bf16 conversion ----------------
__global__ __launch_bounds__(1024) void k_pool(
    const float* __restrict__ seq,
    const int* __restrict__ idxr, const int* __restrict__ lenr,
    const int* __restrict__ idxn, const int* __restrict__ lenn,
    const int* __restrict__ idxd, const int* __restrict__ lend,
    const float* __restrict__ dWr, const float* __restrict__ dWn,
    const float* __restrict__ dWd,
    const float* __restrict__ cbr, const float* __restrict__ cbn,
    const float* __restrict__ cbd,
    unsigned short* __restrict__ dWb,      // [3][768][768] bf16
    unsigned short* __restrict__ pooledb,  // [3][64][768] bf16
    float* __restrict__ out)               // bias-init; K2 atomicAdds partials
{
    const int b = blockIdx.x, g = blockIdx.y;
    const int tid = threadIdx.x, lane = tid & 63, wave = tid >> 6;  // 16 waves

    const int* idxp = (g == 0) ? idxr : (g == 1) ? idxn : idxd;
    const int* lnp  = (g == 0) ? lenr : (g == 1) ? lenn : lend;

    __shared__ int   sidx[Kdim];
    __shared__ float wm[16], wl[16], coef[16];
    __shared__ float wpart[16][Hdim];   // 48 KB

    if (tid < Kdim) sidx[tid] = idxp[b * Kdim + tid];
    const int len = lnp[b];

    if (b == 0) {  // bias-init of out (stream-ordered before K2's atomics)
        if (g == 0)      { if (tid < 576) out[tid]       = cbr[tid % 9]; }
        else if (g == 1) { if (tid < 192) out[576 + tid] = cbn[tid % 3]; }
        else             { if (tid < 192) out[768 + tid] = cbd[tid % 3]; }
    }
    __syncthreads();

    unsigned short* pb = pooledb + ((size_t)g * Bdim + b) * Hdim;

    if (len > 0) {
        const float* row0 = seq + ((size_t)b * Sdim + sidx[0]) * Hdim;
        float g0[12];
#pragma unroll
        for (int k = 0; k < 3; ++k) {
            float4 t = *(const float4*)(row0 + 4 * lane + 256 * k);
            g0[4 * k + 0] = t.x; g0[4 * k + 1] = t.y;
            g0[4 * k + 2] = t.z; g0[4 * k + 3] = t.w;
        }

        // <=4 rows per wave; loads predicated WAVE-UNIFORMLY (j<len), all
        // issued together. v zero-init so masked t contributes exact 0.
        float v[4][12];
#pragma unroll
        for (int t = 0; t < 4; ++t)
#pragma unroll
            for (int k = 0; k < 12; ++k) v[t][k] = 0.f;

#pragma unroll
        for (int t = 0; t < 4; ++t) {
            int j = wave + 16 * t;
            if (j < len) {   // wave-uniform: s_cbranch, no divergence
                const float* rowj = seq + ((size_t)b * Sdim + sidx[j]) * Hdim + 4 * lane;
#pragma unroll
                for (int k = 0; k < 3; ++k) {
                    float4 x = *(const float4*)(rowj + 256 * k);
                    v[t][4 * k + 0] = x.x; v[t][4 * k + 1] = x.y;
                    v[t][4 * k + 2] = x.z; v[t][4 * k + 3] = x.w;
                }
            }
        }

        float s[4];
#pragma unroll
        for (int t = 0; t < 4; ++t) {
            float a = 0.f;
#pragma unroll
            for (int k = 0; k < 12; ++k) a += g0[k] * v[t][k];
            s[t] = a;
        }
        // interleaved butterflies: 4-way ILP on the shuffle chain
#pragma unroll
        for (int off = 32; off > 0; off >>= 1)
#pragma unroll
            for (int t = 0; t < 4; ++t) s[t] += __shfl_xor(s[t], off, 64);

#pragma unroll
        for (int t = 0; t < 4; ++t)
            if (wave + 16 * t >= len) s[t] = -1e30f;

        float m = fmaxf(fmaxf(s[0], s[1]), fmaxf(s[2], s[3]));
        float e[4], l = 0.f;
#pragma unroll
        for (int t = 0; t < 4; ++t) {
            e[t] = (wave + 16 * t < len) ? __expf(s[t] - m) : 0.f;
            l += e[t];
        }
        float p[12];
#pragma unroll
        for (int k = 0; k < 12; ++k)
            p[k] = e[0] * v[0][k] + e[1] * v[1][k] + e[2] * v[2][k] + e[3] * v[3][k];

        if (lane == 0) { wm[wave] = m; wl[wave] = l; }
#pragma unroll
        for (int k = 0; k < 3; ++k)
            *(float4*)&wpart[wave][4 * lane + 256 * k] =
                make_float4(p[4 * k], p[4 * k + 1], p[4 * k + 2], p[4 * k + 3]);
        __syncthreads();

        if (wave == 0 && lane < 16) {
            float mw = wm[lane], lw = wl[lane];
            float M = mw;
#pragma unroll
            for (int off = 8; off > 0; off >>= 1) M = fmaxf(M, __shfl_xor(M, off, 64));
            float sc = __expf(mw - M);        // 0 for waves with no j (mw=-1e30)
            float Ls = lw * sc;
#pragma unroll
            for (int off = 8; off > 0; off >>= 1) Ls += __shfl_xor(Ls, off, 64);
            coef[lane] = sc / Ls;
        }
        __syncthreads();

        if (tid < Hdim) {
            float acc = 0.f;
#pragma unroll
            for (int w = 0; w < 16; ++w) acc += wpart[w][tid] * coef[w];
            pb[tid] = f2bf(acc);
        }
    } else {
        if (tid < Hdim) pb[tid] = f2bf(seq[(size_t)b * Sdim * Hdim + tid]);
    }

    // ---- dW f32->bf16 conversion, spread over the grid's idle capacity ----
    // block (b,g) converts rows [12b, 12b+12) of dW_g: coalesced f32 reads,
    // 1.5KB bf16 writes. Same f2bf as the old K2 staging => bit-identical.
    {
        const float* dWsrc = (g == 0) ? dWr : (g == 1) ? dWn : dWd;
        unsigned short* dWdst = dWb + (size_t)g * Hdim * Hdim;
        if (tid < Hdim) {
#pragma unroll
            for (int r = 0; r < 12; ++r) {
                size_t o = (size_t)(b * 12 + r) * Hdim + tid;
                dWdst[o] = f2bf(dWsrc[o]);
            }
        }
    }
}

// ---------------- K2: single-stage bf16 MFMA dense+tanh + classifier ----------------
__global__ __launch_bounds__(512) void k_dense_cls(
    const unsigned short* __restrict__ dWb,      // [3][768][768] bf16
    const unsigned short* __restrict__ pooledb,  // [3][64][768] bf16
    const float* __restrict__ dbr, const float* __restrict__ cWr,
    const float* __restrict__ dbn, const float* __restrict__ cWn,
    const float* __restrict__ dbd, const float* __restrict__ cWd,
    float* __restrict__ out)
{
    const int mt = blockIdx.x, g = blockIdx.y;
    const float *db, *cW; int nlab, off;
    if (g == 0)      { db = dbr; cW = cWr; nlab = 9; off = 0;   }
    else if (g == 1) { db = dbn; cW = cWn; nlab = 3; off = 576; }
    else             { db = dbd; cW = cWd; nlab = 3; off = 768; }
    const int i0 = mt * 64;

    const int tid = threadIdx.x, lane = tid & 63, wv = tid >> 6;  // 8 waves
    const int col = lane & 15, q = lane >> 4;
    const int kq = wv >> 2, m = wv & 3;   // K-half, m-subtile

    // P panel: 64 rows(b) x 768 k bf16, XOR-swizzled: byte ^= (row&7)<<4.
    // Conflict-free (optimal 8cy) for BOTH the staging ds_write_b128 and the
    // B-fragment ds_read_b128 (derivation: bank-span index = q^(row&7)).
    __shared__ __align__(16) char PsB[64 * 1536];  // 96 KB
    __shared__ float P1[64][65];                   // kq=1 partial, 16.6 KB
    __shared__ float hs[64][65];                   // h-tile, 16.6 KB

    // A fragments: straight from global bf16, held in 48 VGPRs all kernel.
    // Layout identical to old verified LDS read: row = i0+m*16+col,
    // k = kq*384 + ks*32 + 8q + [0..7].
    const unsigned short* Ag = dWb + (size_t)g * Hdim * Hdim;
    const unsigned short* ab = Ag + (size_t)(i0 + m * 16 + col) * Hdim + kq * 384 + q * 8;
    bf16x8 a_reg[12];
#pragma unroll
    for (int ks = 0; ks < 12; ++ks)
        a_reg[ks] = *(const bf16x8*)(ab + ks * 32);

    // stage P panel once (512 thr: 8 thr/row x 12 x 16B)
    {
        const unsigned short* Pg = pooledb + (size_t)g * Bdim * Hdim;
        const int row = tid >> 3, seg = tid & 7;
        const unsigned short* src = Pg + (size_t)row * Hdim + seg * 8;
        const int rb = row * 1536, sw = (row & 7) << 4;
#pragma unroll
        for (int j = 0; j < 12; ++j) {
            bf16x8 v = *(const bf16x8*)(src + j * 64);
            *(bf16x8*)(PsB + ((rb + j * 128 + seg * 16) ^ sw)) = v;
        }
    }
    __syncthreads();

    f32x4 acc[4] = {{0,0,0,0},{0,0,0,0},{0,0,0,0},{0,0,0,0}};
#pragma unroll
    for (int ks = 0; ks < 12; ++ks) {
#pragma unroll
        for (int n = 0; n < 4; ++n) {
            const int row = n * 16 + col;
            const int bo = (row * 1536 + kq * 768 + ks * 64 + q * 16) ^ ((row & 7) << 4);
            bf16x8 bb = *(const bf16x8*)(PsB + bo);
            acc[n] = __builtin_amdgcn_mfma_f32_16x16x32_bf16(a_reg[ks], bb, acc[n], 0, 0, 0);
        }
    }

    // K-half reduce: kq=1 parks partials in LDS, kq=0 finishes + tanh.
    if (kq == 1) {
#pragma unroll
        for (int n = 0; n < 4; ++n)
#pragma unroll
            for (int r = 0; r < 4; ++r)
                P1[m * 16 + q * 4 + r][n * 16 + col] = acc[n][r];
    }
    __syncthreads();
    if (kq == 0) {
#pragma unroll
        for (int n = 0; n < 4; ++n) {
            const int bb2 = n * 16 + col;
#pragma unroll
            for (int r = 0; r < 4; ++r) {
                const int il = m * 16 + q * 4 + r;
                hs[il][bb2] = tanhf(acc[n][r] + P1[il][bb2] + db[i0 + il]);
            }
        }
    }
    __syncthreads();

    // classifier partial: out[b][c] += sum_il cW[c][i0+il]*h[il][b]
    for (int c = wv; c < nlab; c += 8) {
        const float* wr = cW + (size_t)c * Hdim + i0;
        float a = 0.f;
#pragma unroll 16
        for (int il = 0; il < 64; ++il)
            a += wr[il] * hs[il][lane];
        atomicAdd(&out[off + lane * nlab + c], a);
    }
}

extern "C" void kernel_launch(void* const* d_in, const int* in_sizes, int n_in,
                              void* d_out, int out_size, void* d_ws, size_t ws_size,
                              hipStream_t stream) {
    const float* seq  = (const float*)d_in[0];
    const int*   idxr = (const int*)d_in[1];
    const int*   lenr = (const int*)d_in[2];
    const int*   idxn = (const int*)d_in[3];
    const int*   lenn = (const int*)d_in[4];
    const int*   idxd = (const int*)d_in[5];
    const int*   lend = (const int*)d_in[6];
    const float* dWr  = (const float*)d_in[7];
    const float* dbr  = (const float*)d_in[8];
    const float* cWr  = (const float*)d_in[9];
    const float* cbr  = (const float*)d_in[10];
    const float* dWn  = (const float*)d_in[11];
    const float* dbn  = (const float*)d_in[12];
    const float* cWn  = (const float*)d_in[13];
    const float* cbn  = (const float*)d_in[14];
    const float* dWd  = (const float*)d_in[15];
    const float* dbd  = (const float*)d_in[16];
    const float* cWd  = (const float*)d_in[17];
    const float* cbd  = (const float*)d_in[18];
    float* out = (float*)d_out;

    // workspace: [0, 3.38MB) dW bf16; then pooled bf16 (3*64*768*2 = 288KB)
    unsigned short* dWb     = (unsigned short*)d_ws;
    unsigned short* pooledb = (unsigned short*)((char*)d_ws + (size_t)3 * Hdim * Hdim * 2);

    k_pool<<<dim3(Bdim, 3), 1024, 0, stream>>>(
        seq, idxr, lenr, idxn, lenn, idxd, lend,
        dWr, dWn, dWd, cbr, cbn, cbd, dWb, pooledb, out);
    k_dense_cls<<<dim3(Hdim / 64, 3), 512, 0, stream>>>(
        dWb, pooledb, dbr, cWr, dbn, cWn, dbd, cWd, out);
}